// Round 10
// baseline (2180.948 us; speedup 1.0000x reference)
//
#include <hip/hip_runtime.h>
#include <math.h>

#define B_    16
#define T_    4096
#define C_    256
#define CIN1  80
#define EMB   128
#define TP    341
#define NPOS  (B_*TP)      // 5456
#define NQ_   8
#define KCB   256
#define BN_EPS 1e-5

// ---------------- prep kernels ----------------
__global__ __launch_bounds__(256) void prep_common(
    const float* __restrict__ wd,
    const float* __restrict__ b1, const float* __restrict__ g1,
    const float* __restrict__ be1, const float* __restrict__ m1,
    const float* __restrict__ v1,
    const float* __restrict__ b2, const float* __restrict__ g2,
    const float* __restrict__ be2, const float* __restrict__ m2,
    const float* __restrict__ v2,
    float* __restrict__ wdt,
    double* __restrict__ a1, double* __restrict__ bt1,
    double* __restrict__ a2, double* __restrict__ bt2)
{
    int j = blockIdx.x * 256 + threadIdx.x;
    if (j < 256*24*128) wdt[j] = wd[(size_t)(j & 127) * 6144 + (j >> 7)];
    if (j < 256) {
        double inv1 = 1.0 / sqrt((double)v1[j] + BN_EPS);
        double s1 = (double)g1[j] * inv1;
        a1[j]  = s1;
        bt1[j] = ((double)b1[j] - (double)m1[j]) * s1 + (double)be1[j];
        double inv2 = 1.0 / sqrt((double)v2[j] + BN_EPS);
        double s2 = (double)g2[j] * inv2;
        a2[j]  = s2;
        bt2[j] = ((double)b2[j] - (double)m2[j]) * s2 + (double)be2[j];
    }
}

// transposed weight tables: [(ci*5+k)*256 + co]
__global__ __launch_bounds__(256) void prep_wf64(
    const float* __restrict__ w1, const float* __restrict__ w2,
    double* __restrict__ w1td, double* __restrict__ w2td)
{
    int j = blockIdx.x * 256 + threadIdx.x;
    if (j < 256*5*256) w2td[j] = (double)w2[(size_t)(j & 255) * 1280 + (j >> 8)];
    if (j < 80*5*256)  w1td[j] = (double)w1[(size_t)(j & 255) * 400 + (j >> 8)];
}
__global__ __launch_bounds__(256) void prep_wf32(
    const float* __restrict__ w1, const float* __restrict__ w2,
    float* __restrict__ w1tf, float* __restrict__ w2tf)
{
    int j = blockIdx.x * 256 + threadIdx.x;
    if (j < 256*5*256) w2tf[j] = w2[(size_t)(j & 255) * 1280 + (j >> 8)];
    if (j < 80*5*256)  w1tf[j] = w1[(size_t)(j & 255) * 400 + (j >> 8)];
}

// bank swizzle on 16B granularity (convd only)
__device__ __forceinline__ int swz_pair(int col) {        // col even (f64 idx)
    int bw = col >> 1;
    return ((bw ^ ((bw >> 3) & 7)) << 1);
}
__device__ __forceinline__ int swz_scalar(int col) {      // any f64 idx
    int bw = col >> 1;
    return (((bw ^ ((bw >> 3) & 7)) << 1) | (col & 1));
}

// ---------------- f64 conv(k=5,pad=2) + BN + ReLU, v11 ----------------
// LDS-free; wave = 64 lanes x 2 t (128 t), wave owns 16-co strip (w wave-uniform
// -> scalar pipe). 1-D grid with XCD grouping: the 4 co-tiles of one (b,t)-window
// share an XCD -> x reads hit that XCD's L2. ci unrolled x2 with x double-buffer.
// id = (((g>>3)*4 + cot) << 3) | (g&7), g = b*32 + t-tile.
template<int CIN, typename Tin, typename WT>
__global__ __launch_bounds__(256, 4) void conv5_v11(
    const Tin* __restrict__ in,       // [nb][CIN][T]
    const WT* __restrict__ wt,        // [(ci*5+k)][256]
    const double* __restrict__ alpha, const double* __restrict__ beta,
    double* __restrict__ out)         // [nb][256][T]
{
    const int id  = blockIdx.x;
    const int low = id & 7;
    const int hi  = id >> 3;
    const int cot = hi & 3;
    const int g   = ((hi >> 2) << 3) | low;
    const int b   = g >> 5;
    const int t0  = (g & 31) * 128;

    const int wv = __builtin_amdgcn_readfirstlane((int)(threadIdx.x >> 6));
    const int lane = threadIdx.x & 63;
    const int co0 = cot * 64 + wv * 16;
    const int t = t0 + lane * 2;

    double acc[16][2];
    #pragma unroll
    for (int c = 0; c < 16; ++c) { acc[c][0] = 0.0; acc[c][1] = 0.0; }

    const Tin* xb = in + (size_t)b * CIN * T_ + (t - 2);
    const bool interior = (t0 != 0) && (t0 + 130 <= T_);

    double xv0[6], xv1[6];
    // load x for a given ci into xv
    #define LOADX(CI, XV)                                                \
        {                                                                \
            const Tin* xp = xb + (size_t)(CI) * T_;                      \
            if (interior) {                                              \
                _Pragma("unroll")                                        \
                for (int d = 0; d < 6; ++d) XV[d] = (double)xp[d];       \
            } else {                                                     \
                _Pragma("unroll")                                        \
                for (int d = 0; d < 6; ++d) {                            \
                    int tt = t - 2 + d;                                  \
                    XV[d] = (tt >= 0 && tt < T_) ? (double)xp[d] : 0.0;  \
                }                                                        \
            }                                                            \
        }

    LOADX(0, xv0);
    for (int ci = 0; ci < CIN; ci += 2) {
        LOADX(ci + 1, xv1);
        const WT* wrow = wt + (size_t)ci * 5 * 256 + co0;
        #pragma unroll
        for (int k = 0; k < 5; ++k) {
            #pragma unroll
            for (int c = 0; c < 16; ++c) {
                double w = (double)wrow[k * 256 + c];
                acc[c][0] = fma(w, xv0[k],     acc[c][0]);
                acc[c][1] = fma(w, xv0[k + 1], acc[c][1]);
            }
        }
        if (ci + 2 < CIN) LOADX(ci + 2, xv0);
        wrow += 5 * 256;
        #pragma unroll
        for (int k = 0; k < 5; ++k) {
            #pragma unroll
            for (int c = 0; c < 16; ++c) {
                double w = (double)wrow[k * 256 + c];
                acc[c][0] = fma(w, xv1[k],     acc[c][0]);
                acc[c][1] = fma(w, xv1[k + 1], acc[c][1]);
            }
        }
    }
    #undef LOADX

    #pragma unroll
    for (int c = 0; c < 16; ++c) {
        int co = co0 + c;
        double a = alpha[co], bt = beta[co];
        double y0 = fma(acc[c][0], a, bt);
        double y1 = fma(acc[c][1], a, bt);
        double2 o;
        o.x = y0 > 0.0 ? y0 : 0.0;
        o.y = y1 > 0.0 ? y1 : 0.0;
        *(double2*)&out[((size_t)(b * C_ + co)) * T_ + t] = o;
    }
}

// ---------------- f64 downsample conv v7: k=24, stride=12, pad=6 ----------------
// block: 128 co x 128 tp. 256 thr: tcol=tid&15 (8 tp), crow=tid>>4 (8 co).
// x staged kpos-major + swizzle -> conflict-free. chunk = 1 ci.
__global__ __launch_bounds__(256, 2) void convd_f64_v7(
    const double* __restrict__ x2,    // [nb][256][T]
    const float* __restrict__ wdt,    // f32 [(ci*24+k)][128]
    double* __restrict__ parts,       // [nsplit][nb][128][341]
    int nb, int nsplit, int cis)
{
    const int bz  = blockIdx.z;
    const int s   = bz % nsplit;
    const int b   = bz / nsplit;
    const int tp0 = blockIdx.x * 128;
    const int tid = threadIdx.x;
    const int tcol = tid & 15;
    const int crow = tid >> 4;

    __shared__ __align__(16) double xs2[24][132]; // kpos-major, swizzled cols
    __shared__ __align__(16) double wsh[24][128];

    double acc[8][8];
    #pragma unroll
    for (int i = 0; i < 8; ++i)
        #pragma unroll
        for (int j = 0; j < 8; ++j) acc[i][j] = 0.0;

    const int tbase = tp0 * 12 - 6;
    const int ci_begin = s * cis;

    for (int c = ci_begin; c < ci_begin + cis; ++c) {
        for (int i = tid; i < 1548; i += 256) {
            int t = tbase + i;
            double v = (t >= 0 && t < T_)
                ? x2[((size_t)(b * 256 + c)) * T_ + t] : 0.0;
            int tp = (i * 43691) >> 19;           // i/12
            int kp = i - tp * 12;
            xs2[kp][swz_scalar(tp)] = v;
            if (tp >= 1) xs2[kp + 12][swz_scalar(tp - 1)] = v;
        }
        for (int i = tid; i < 24 * 128; i += 256) {
            int r = i >> 7, cc = i & 127;
            wsh[r][cc] = (double)wdt[((size_t)c * 24 + r) * 128 + cc];
        }
        __syncthreads();

        #pragma unroll 4
        for (int k = 0; k < 24; ++k) {
            double wv[8];
            #pragma unroll
            for (int m = 0; m < 4; ++m) {
                double2 w2v = *(const double2*)&wsh[k][crow * 8 + 2 * m];
                wv[2 * m] = w2v.x; wv[2 * m + 1] = w2v.y;
            }
            #pragma unroll
            for (int jp = 0; jp < 4; ++jp) {
                double2 xp = *(const double2*)&xs2[k][swz_pair(tcol * 2 + 32 * jp)];
                #pragma unroll
                for (int i = 0; i < 8; ++i) {
                    acc[i][jp * 2]     = fma(wv[i], xp.x, acc[i][jp * 2]);
                    acc[i][jp * 2 + 1] = fma(wv[i], xp.y, acc[i][jp * 2 + 1]);
                }
            }
        }
        __syncthreads();
    }

    #pragma unroll
    for (int i = 0; i < 8; ++i) {
        int co = crow * 8 + i;
        #pragma unroll
        for (int jp = 0; jp < 4; ++jp) {
            #pragma unroll
            for (int e = 0; e < 2; ++e) {
                int tp = tp0 + tcol * 2 + 32 * jp + e;
                if (tp < TP)
                    parts[(((size_t)s * nb + b) * EMB + co) * TP + tp] = acc[i][jp * 2 + e];
            }
        }
    }
}

// ---------------- combine partials + bias -> parts[0] (=e, f64) + e_out (f32) ----
__global__ __launch_bounds__(256) void convd_combine(
    double* __restrict__ parts,       // [nsplit][nb][128][341]; writes slot 0
    const float* __restrict__ bd,
    float* __restrict__ e_out,        // [16][128][341]
    int nb, int b_off, int nsplit)
{
    int idx = blockIdx.x * 256 + threadIdx.x;
    int total = nb * EMB * TP;
    if (idx >= total) return;
    int rem = idx % (EMB * TP);
    int co = rem / TP;
    size_t stride = (size_t)nb * EMB * TP;
    double y = 0.0;
    for (int s = 0; s < nsplit; ++s)     // ascending s: deterministic
        y += parts[(size_t)s * stride + idx];
    y += (double)bd[co];
    parts[idx] = y;                      // in-place e (f64)
    e_out[(size_t)b_off * EMB * TP + idx] = (float)y;
}

// ---------------- f64 1x1 projection (per group) ----------------
__global__ __launch_bounds__(128) void zproj_f64(
    const double* __restrict__ ed,    // [nb][128][341]  (= parts[0])
    const float* __restrict__ wp,     // [16][128] f32
    const float* __restrict__ bp,     // [16] f32
    double* __restrict__ z)           // [nb][341][16]
{
    const int b = blockIdx.y;
    const int t = blockIdx.x * 128 + threadIdx.x;
    __shared__ double wps[16][128];
    for (int i = threadIdx.x; i < 16 * 128; i += 128)
        wps[i >> 7][i & 127] = (double)wp[i];
    __syncthreads();
    if (t >= TP) return;
    double acc[16];
    #pragma unroll
    for (int v = 0; v < 16; ++v) acc[v] = (double)bp[v];
    for (int co = 0; co < 128; ++co) {
        double x = ed[((size_t)(b * EMB + co)) * TP + t];
        #pragma unroll
        for (int v = 0; v < 16; ++v) acc[v] = fma(x, wps[v][co], acc[v]);
    }
    #pragma unroll
    for (int v = 0; v < 16; ++v)
        z[((size_t)(b * TP + t)) * 16 + v] = acc[v];
}

// ---------------- RVQ: f64 distances, wave-shuffle argmin ----------------
__global__ __launch_bounds__(256) void rvq_f64_v2(
    const double* __restrict__ z,     // [NPOS][16]
    const float* __restrict__ cb,     // [8][256][16]
    float* __restrict__ out_idx)      // [8][NPOS] as float
{
    const int pos = blockIdx.x;
    const int tid = threadIdx.x;
    const int lane = tid & 63;
    const int wv = tid >> 6;

    __shared__ double r[16];
    __shared__ double wd_s[4];
    __shared__ int wi_s[4];
    __shared__ int best_s;

    if (tid < 16) r[tid] = z[(size_t)pos * 16 + tid];
    __syncthreads();

    for (int q = 0; q < NQ_; ++q) {
        const float* c = cb + ((size_t)(q * KCB) + tid) * 16;
        double d = 0.0;
        #pragma unroll
        for (int i = 0; i < 16; ++i) {
            double diff = r[i] - (double)c[i];
            d = fma(diff, diff, d);
        }
        int idx = tid;
        #pragma unroll
        for (int sft = 32; sft > 0; sft >>= 1) {
            double d2 = __shfl_down(d, sft, 64);
            int i2 = __shfl_down(idx, sft, 64);
            if (d2 < d || (d2 == d && i2 < idx)) { d = d2; idx = i2; }
        }
        if (lane == 0) { wd_s[wv] = d; wi_s[wv] = idx; }
        __syncthreads();
        if (tid == 0) {
            double bd_ = wd_s[0]; int bi = wi_s[0];
            #pragma unroll
            for (int w = 1; w < 4; ++w) {
                if (wd_s[w] < bd_ || (wd_s[w] == bd_ && wi_s[w] < bi)) {
                    bd_ = wd_s[w]; bi = wi_s[w];
                }
            }
            best_s = bi;
            out_idx[(size_t)q * NPOS + pos] = (float)bi;
        }
        __syncthreads();
        int best = best_s;
        if (tid < 16)
            r[tid] = r[tid] - (double)cb[((size_t)(q * KCB) + best) * 16 + tid];
        __syncthreads();
    }
}

// ---------------- host launcher ----------------
extern "C" void kernel_launch(void* const* d_in, const int* in_sizes, int n_in,
                              void* d_out, int out_size, void* d_ws, size_t ws_size,
                              hipStream_t stream) {
    const float* mel = (const float*)d_in[0];
    const float* w1  = (const float*)d_in[1];
    const float* b1  = (const float*)d_in[2];
    const float* g1  = (const float*)d_in[3];
    const float* be1 = (const float*)d_in[4];
    const float* m1  = (const float*)d_in[5];
    const float* v1  = (const float*)d_in[6];
    const float* w2  = (const float*)d_in[7];
    const float* b2  = (const float*)d_in[8];
    const float* g2  = (const float*)d_in[9];
    const float* be2 = (const float*)d_in[10];
    const float* m2  = (const float*)d_in[11];
    const float* v2  = (const float*)d_in[12];
    const float* wd  = (const float*)d_in[13];
    const float* bd  = (const float*)d_in[14];
    const float* wp  = (const float*)d_in[15];
    const float* bp  = (const float*)d_in[16];
    const float* cb  = (const float*)d_in[17];

    const int nb = 8;                  // batches per group
    const int ngrp = B_ / nb;          // 2
    const int nsplit = 16;
    const int cis = 256 / nsplit;

    const size_t x1_bytes = (size_t)nb * C_ * T_ * 8;   // 67,108,864 (shared w/ parts)
    const size_t x2_bytes = (size_t)nb * C_ * T_ * 8;   // 67,108,864
    const size_t zd_bytes = (size_t)B_ * TP * 16 * 8;   // 698,368

    // tier A: f64 weight tables; tier B: f32 tables + in-kernel cvt
    const size_t needA = x1_bytes + x2_bytes + (size_t)80*5*256*8
                       + (size_t)256*5*256*8 + (size_t)256*24*128*4
                       + 4*2048 + zd_bytes + 8192;      // ~139.95 MB
    const bool tierA = (ws_size >= needA);

    char* ws = (char*)d_ws;
    size_t off = 0;
    auto alloc = [&](size_t bytes) -> char* {
        char* p = ws + off;
        off = (off + bytes + 255) & ~(size_t)255;
        return p;
    };
    char* shared = alloc(x1_bytes);
    double* x1d  = (double*)shared;     // dead when convd runs
    double* parts= (double*)shared;     // aliases x1; parts[0] becomes e (f64)
    double* x2d  = (double*)alloc(x2_bytes);
    void*   w1t  = (void*)alloc(tierA ? (size_t)80*5*256*8  : (size_t)80*5*256*4);
    void*   w2t  = (void*)alloc(tierA ? (size_t)256*5*256*8 : (size_t)256*5*256*4);
    float*  wdt  = (float*)alloc((size_t)256*24*128*4);
    double* a1d  = (double*)alloc(2048);
    double* bt1d = (double*)alloc(2048);
    double* a2d  = (double*)alloc(2048);
    double* bt2d = (double*)alloc(2048);
    double* zd   = (double*)alloc(zd_bytes);

    float* e_out   = (float*)d_out;                          // [16][128][341]
    float* idx_out = (float*)d_out + (size_t)B_ * EMB * TP;  // [8][16][341]

    prep_common<<<3072, 256, 0, stream>>>(wd, b1, g1, be1, m1, v1,
                                          b2, g2, be2, m2, v2,
                                          wdt, a1d, bt1d, a2d, bt2d);
    if (tierA)
        prep_wf64<<<1280, 256, 0, stream>>>(w1, w2, (double*)w1t, (double*)w2t);
    else
        prep_wf32<<<1280, 256, 0, stream>>>(w1, w2, (float*)w1t, (float*)w2t);

    const int comb_blocks = (nb * EMB * TP + 255) / 256;
    const int conv_blocks = 4 * 32 * nb;      // 1024
    for (int g = 0; g < ngrp; ++g) {
        const float* mel_g = mel + (size_t)(g * nb) * CIN1 * T_;
        if (tierA) {
            conv5_v11<CIN1, float, double><<<conv_blocks, 256, 0, stream>>>(
                mel_g, (const double*)w1t, a1d, bt1d, x1d);
            conv5_v11<C_, double, double><<<conv_blocks, 256, 0, stream>>>(
                x1d, (const double*)w2t, a2d, bt2d, x2d);
        } else {
            conv5_v11<CIN1, float, float><<<conv_blocks, 256, 0, stream>>>(
                mel_g, (const float*)w1t, a1d, bt1d, x1d);
            conv5_v11<C_, double, float><<<conv_blocks, 256, 0, stream>>>(
                x1d, (const float*)w2t, a2d, bt2d, x2d);
        }
        // x1 dead from here -> parts may reuse it
        convd_f64_v7<<<dim3(3, 1, nb * nsplit), 256, 0, stream>>>(
            x2d, wdt, parts, nb, nsplit, cis);
        convd_combine<<<comb_blocks, 256, 0, stream>>>(
            parts, bd, e_out, nb, g * nb, nsplit);
        zproj_f64<<<dim3(3, nb), 128, 0, stream>>>(
            parts, wp, bp, zd + (size_t)g * nb * TP * 16);
    }
    rvq_f64_v2<<<NPOS, 256, 0, stream>>>(zd, cb, idx_out);
}

// Round 11
// 1790.242 us; speedup vs baseline: 1.2182x; 1.2182x over previous
//
#include <hip/hip_runtime.h>
#include <math.h>

#define B_    16
#define T_    4096
#define C_    256
#define CIN1  80
#define EMB   128
#define TP    341
#define NPOS  (B_*TP)      // 5456
#define NQ_   8
#define KCB   256
#define BN_EPS 1e-5

// ---------------- prep: f32 transposes (lossless) + f64 BN fold ----------------
__global__ __launch_bounds__(256) void prep_v11(
    const float* __restrict__ w1, const float* __restrict__ w2,
    const float* __restrict__ wd,
    const float* __restrict__ b1, const float* __restrict__ g1,
    const float* __restrict__ be1, const float* __restrict__ m1,
    const float* __restrict__ v1,
    const float* __restrict__ b2, const float* __restrict__ g2,
    const float* __restrict__ be2, const float* __restrict__ m2,
    const float* __restrict__ v2,
    float* __restrict__ w1t, float* __restrict__ w2t, float* __restrict__ wdt,
    double* __restrict__ a1, double* __restrict__ bt1,
    double* __restrict__ a2, double* __restrict__ bt2)
{
    int j = blockIdx.x * 256 + threadIdx.x;
    if (j < 256*24*128) wdt[j] = wd[(size_t)(j & 127) * 6144 + (j >> 7)];
    if (j < 256*5*256)  w2t[j] = w2[(size_t)(j & 255) * 1280 + (j >> 8)];
    if (j < 80*5*256)   w1t[j] = w1[(size_t)(j & 255) * 400 + (j >> 8)];
    if (j < 256) {
        double inv1 = 1.0 / sqrt((double)v1[j] + BN_EPS);
        double s1 = (double)g1[j] * inv1;
        a1[j]  = s1;
        bt1[j] = ((double)b1[j] - (double)m1[j]) * s1 + (double)be1[j];
        double inv2 = 1.0 / sqrt((double)v2[j] + BN_EPS);
        double s2 = (double)g2[j] * inv2;
        a2[j]  = s2;
        bt2[j] = ((double)b2[j] - (double)m2[j]) * s2 + (double)be2[j];
    }
}

// bank swizzle on 16B granularity (within 128B groups)
__device__ __forceinline__ int swz_pair(int col) {        // col even (f64 idx)
    int bw = col >> 1;
    return ((bw ^ ((bw >> 3) & 7)) << 1);
}
__device__ __forceinline__ int swz_scalar(int col) {      // any f64 idx
    int bw = col >> 1;
    return (((bw ^ ((bw >> 3) & 7)) << 1) | (col & 1));
}

// ---------------- f64 conv(k=5,pad=2) + BN + ReLU, v8 ----------------
// block: 64 co x 256 t. 256 thr: tcol=tid&15 (16 t each), trow=tid>>4 (4 co).
// Per ci: w fully hoisted to regs (10 double2), x in two 6-double2 halves.
// wt is transposed f32 [(ci*5+k)][256].
template<int CIN, typename Tin>
__global__ __launch_bounds__(256, 2) void conv5_v8(
    const Tin* __restrict__ in,       // [nb][CIN][T]
    const float* __restrict__ wt,
    const double* __restrict__ alpha, const double* __restrict__ beta,
    double* __restrict__ out)         // [nb][256][T]
{
    const int b   = blockIdx.z;
    const int co0 = blockIdx.y * 64;
    const int t0  = blockIdx.x * 256;
    const int tid = threadIdx.x;
    const int tcol = tid & 15;
    const int trow = tid >> 4;

    __shared__ __align__(16) double xs[8][264];   // 260 used (halo 2+2), swizzled
    __shared__ __align__(16) double wsh[40][64];

    double acc[4][16];
    #pragma unroll
    for (int i = 0; i < 4; ++i)
        #pragma unroll
        for (int j = 0; j < 16; ++j) acc[i][j] = 0.0;

    for (int c0 = 0; c0 < CIN; c0 += 8) {
        for (int i = tid; i < 8 * 260; i += 256) {
            int ci = i / 260, col = i - ci * 260;
            int t = t0 - 2 + col;
            double v = 0.0;
            if (t >= 0 && t < T_) v = (double)in[((size_t)(b * CIN + c0 + ci)) * T_ + t];
            xs[ci][swz_scalar(col)] = v;
        }
        for (int i = tid; i < 40 * 64; i += 256) {
            int r = i >> 6, co = i & 63;
            wsh[r][co] = (double)wt[(size_t)(c0 * 5 + r) * 256 + co0 + co];
        }
        __syncthreads();

        #pragma unroll 2
        for (int ci = 0; ci < 8; ++ci) {
            double wv[20];
            #pragma unroll
            for (int k = 0; k < 5; ++k) {
                double2 wa = *(const double2*)&wsh[ci * 5 + k][trow * 4];
                double2 wb = *(const double2*)&wsh[ci * 5 + k][trow * 4 + 2];
                wv[k * 4 + 0] = wa.x; wv[k * 4 + 1] = wa.y;
                wv[k * 4 + 2] = wb.x; wv[k * 4 + 3] = wb.y;
            }
            #pragma unroll
            for (int h = 0; h < 2; ++h) {
                double xv[12];
                #pragma unroll
                for (int m = 0; m < 6; ++m) {
                    double2 v2 = *(const double2*)&xs[ci][swz_pair(tcol * 16 + h * 8 + 2 * m)];
                    xv[2 * m] = v2.x; xv[2 * m + 1] = v2.y;
                }
                #pragma unroll
                for (int k = 0; k < 5; ++k)
                    #pragma unroll
                    for (int i4 = 0; i4 < 4; ++i4) {
                        double w = wv[k * 4 + i4];
                        #pragma unroll
                        for (int j = 0; j < 8; ++j)
                            acc[i4][h * 8 + j] = fma(w, xv[j + k], acc[i4][h * 8 + j]);
                    }
            }
        }
        __syncthreads();
    }

    const int cobase = co0 + trow * 4;
    const int tg = t0 + tcol * 16;
    #pragma unroll
    for (int i4 = 0; i4 < 4; ++i4) {
        double a = alpha[cobase + i4], bt = beta[cobase + i4];
        size_t base = ((size_t)(b * C_ + cobase + i4)) * T_ + tg;
        #pragma unroll
        for (int m = 0; m < 8; ++m) {
            double2 o;
            double y0 = fma(acc[i4][2 * m], a, bt);
            double y1 = fma(acc[i4][2 * m + 1], a, bt);
            o.x = y0 > 0.0 ? y0 : 0.0;
            o.y = y1 > 0.0 ? y1 : 0.0;
            *(double2*)&out[base + 2 * m] = o;
        }
    }
}

// ---------------- f64 downsample conv v7: k=24, stride=12, pad=6 ----------------
// block: 128 co x 128 tp. 256 thr: tcol=tid&15 (8 tp), crow=tid>>4 (8 co).
// x staged kpos-major + swizzle -> conflict-free. chunk = 1 ci.
__global__ __launch_bounds__(256, 2) void convd_f64_v7(
    const double* __restrict__ x2,    // [nb][256][T]
    const float* __restrict__ wdt,    // f32 [(ci*24+k)][128]
    double* __restrict__ parts,       // [nsplit][nb][128][341]
    int nb, int nsplit, int cis)
{
    const int bz  = blockIdx.z;
    const int s   = bz % nsplit;
    const int b   = bz / nsplit;
    const int tp0 = blockIdx.x * 128;
    const int tid = threadIdx.x;
    const int tcol = tid & 15;
    const int crow = tid >> 4;

    __shared__ __align__(16) double xs2[24][132]; // kpos-major, swizzled cols
    __shared__ __align__(16) double wsh[24][128];

    double acc[8][8];
    #pragma unroll
    for (int i = 0; i < 8; ++i)
        #pragma unroll
        for (int j = 0; j < 8; ++j) acc[i][j] = 0.0;

    const int tbase = tp0 * 12 - 6;
    const int ci_begin = s * cis;

    for (int c = ci_begin; c < ci_begin + cis; ++c) {
        for (int i = tid; i < 1548; i += 256) {
            int t = tbase + i;
            double v = (t >= 0 && t < T_)
                ? x2[((size_t)(b * 256 + c)) * T_ + t] : 0.0;
            int tp = (i * 43691) >> 19;           // i/12
            int kp = i - tp * 12;
            xs2[kp][swz_scalar(tp)] = v;
            if (tp >= 1) xs2[kp + 12][swz_scalar(tp - 1)] = v;
        }
        for (int i = tid; i < 24 * 128; i += 256) {
            int r = i >> 7, cc = i & 127;
            wsh[r][cc] = (double)wdt[((size_t)c * 24 + r) * 128 + cc];
        }
        __syncthreads();

        #pragma unroll 4
        for (int k = 0; k < 24; ++k) {
            double wv[8];
            #pragma unroll
            for (int m = 0; m < 4; ++m) {
                double2 w2v = *(const double2*)&wsh[k][crow * 8 + 2 * m];
                wv[2 * m] = w2v.x; wv[2 * m + 1] = w2v.y;
            }
            #pragma unroll
            for (int jp = 0; jp < 4; ++jp) {
                double2 xp = *(const double2*)&xs2[k][swz_pair(tcol * 2 + 32 * jp)];
                #pragma unroll
                for (int i = 0; i < 8; ++i) {
                    acc[i][jp * 2]     = fma(wv[i], xp.x, acc[i][jp * 2]);
                    acc[i][jp * 2 + 1] = fma(wv[i], xp.y, acc[i][jp * 2 + 1]);
                }
            }
        }
        __syncthreads();
    }

    #pragma unroll
    for (int i = 0; i < 8; ++i) {
        int co = crow * 8 + i;
        #pragma unroll
        for (int jp = 0; jp < 4; ++jp) {
            #pragma unroll
            for (int e = 0; e < 2; ++e) {
                int tp = tp0 + tcol * 2 + 32 * jp + e;
                if (tp < TP)
                    parts[(((size_t)s * nb + b) * EMB + co) * TP + tp] = acc[i][jp * 2 + e];
            }
        }
    }
}

// ---------------- combine partials + bias -> parts[0] (=e, f64) + e_out (f32) ----
__global__ __launch_bounds__(256) void convd_combine(
    double* __restrict__ parts,       // [nsplit][nb][128][341]; writes slot 0
    const float* __restrict__ bd,
    float* __restrict__ e_out,        // [16][128][341]
    int nb, int b_off, int nsplit)
{
    int idx = blockIdx.x * 256 + threadIdx.x;
    int total = nb * EMB * TP;
    if (idx >= total) return;
    int rem = idx % (EMB * TP);
    int co = rem / TP;
    size_t stride = (size_t)nb * EMB * TP;
    double y = 0.0;
    for (int s = 0; s < nsplit; ++s)     // ascending s: deterministic
        y += parts[(size_t)s * stride + idx];
    y += (double)bd[co];
    parts[idx] = y;                      // in-place e (f64)
    e_out[(size_t)b_off * EMB * TP + idx] = (float)y;
}

// ---------------- f64 1x1 projection (per group) ----------------
__global__ __launch_bounds__(128) void zproj_f64(
    const double* __restrict__ ed,    // [nb][128][341]  (= parts[0])
    const float* __restrict__ wp,     // [16][128] f32
    const float* __restrict__ bp,     // [16] f32
    double* __restrict__ z)           // [nb][341][16]
{
    const int b = blockIdx.y;
    const int t = blockIdx.x * 128 + threadIdx.x;
    __shared__ double wps[16][128];
    for (int i = threadIdx.x; i < 16 * 128; i += 128)
        wps[i >> 7][i & 127] = (double)wp[i];
    __syncthreads();
    if (t >= TP) return;
    double acc[16];
    #pragma unroll
    for (int v = 0; v < 16; ++v) acc[v] = (double)bp[v];
    for (int co = 0; co < 128; ++co) {
        double x = ed[((size_t)(b * EMB + co)) * TP + t];
        #pragma unroll
        for (int v = 0; v < 16; ++v) acc[v] = fma(x, wps[v][co], acc[v]);
    }
    #pragma unroll
    for (int v = 0; v < 16; ++v)
        z[((size_t)(b * TP + t)) * 16 + v] = acc[v];
}

// ---------------- RVQ: f64 distances, wave-shuffle argmin (per group) ----------------
__global__ __launch_bounds__(256) void rvq_f64_v3(
    const double* __restrict__ z,     // [npos_local][16]
    const float* __restrict__ cb,     // [8][256][16]
    float* __restrict__ out_idx,      // [8][NPOS] as float
    int pos_off)
{
    const int pos = blockIdx.x;
    const int tid = threadIdx.x;
    const int lane = tid & 63;
    const int wv = tid >> 6;

    __shared__ double r[16];
    __shared__ double wd_s[4];
    __shared__ int wi_s[4];
    __shared__ int best_s;

    if (tid < 16) r[tid] = z[(size_t)pos * 16 + tid];
    __syncthreads();

    for (int q = 0; q < NQ_; ++q) {
        const float* c = cb + ((size_t)(q * KCB) + tid) * 16;
        double d = 0.0;
        #pragma unroll
        for (int i = 0; i < 16; ++i) {
            double diff = r[i] - (double)c[i];
            d = fma(diff, diff, d);
        }
        int idx = tid;
        #pragma unroll
        for (int sft = 32; sft > 0; sft >>= 1) {
            double d2 = __shfl_down(d, sft, 64);
            int i2 = __shfl_down(idx, sft, 64);
            if (d2 < d || (d2 == d && i2 < idx)) { d = d2; idx = i2; }
        }
        if (lane == 0) { wd_s[wv] = d; wi_s[wv] = idx; }
        __syncthreads();
        if (tid == 0) {
            double bd_ = wd_s[0]; int bi = wi_s[0];
            #pragma unroll
            for (int w = 1; w < 4; ++w) {
                if (wd_s[w] < bd_ || (wd_s[w] == bd_ && wi_s[w] < bi)) {
                    bd_ = wd_s[w]; bi = wi_s[w];
                }
            }
            best_s = bi;
            out_idx[(size_t)q * NPOS + pos_off + pos] = (float)bi;
        }
        __syncthreads();
        int best = best_s;
        if (tid < 16)
            r[tid] = r[tid] - (double)cb[((size_t)(q * KCB) + best) * 16 + tid];
        __syncthreads();
    }
}

// ---------------- host launcher ----------------
extern "C" void kernel_launch(void* const* d_in, const int* in_sizes, int n_in,
                              void* d_out, int out_size, void* d_ws, size_t ws_size,
                              hipStream_t stream) {
    const float* mel = (const float*)d_in[0];
    const float* w1  = (const float*)d_in[1];
    const float* b1  = (const float*)d_in[2];
    const float* g1  = (const float*)d_in[3];
    const float* be1 = (const float*)d_in[4];
    const float* m1  = (const float*)d_in[5];
    const float* v1  = (const float*)d_in[6];
    const float* w2  = (const float*)d_in[7];
    const float* b2  = (const float*)d_in[8];
    const float* g2  = (const float*)d_in[9];
    const float* be2 = (const float*)d_in[10];
    const float* m2  = (const float*)d_in[11];
    const float* v2  = (const float*)d_in[12];
    const float* wd  = (const float*)d_in[13];
    const float* bd  = (const float*)d_in[14];
    const float* wp  = (const float*)d_in[15];
    const float* bp  = (const float*)d_in[16];
    const float* cb  = (const float*)d_in[17];

    const int nb = 8;                  // batches per group
    const int ngrp = B_ / nb;          // 2
    const int nsplit = 16;
    const int cis = 256 / nsplit;

    auto al = [](size_t x) { return (x + 255) & ~(size_t)255; };
    const size_t x1_big   = (size_t)nb * C_ * T_ * 8;            // 67,108,864
    const size_t x1_small = (size_t)4  * C_ * T_ * 8;            // 33,554,432
    const size_t parts_b  = (size_t)nsplit * nb * EMB * TP * 8;  // 44,695,552
    const size_t zd_b     = (size_t)nb * TP * 16 * 8;            // 349,184 (per group)
    const size_t x2_bytes = (size_t)nb * C_ * T_ * 8;
    // zd lives in the parts-region tail (offset parts_b), per group
    const size_t sh_small = (parts_b + zd_b > x1_small) ? (parts_b + zd_b) : x1_small;
    const size_t tail = al((size_t)80*5*256*4)    // w1t f32
                      + al((size_t)256*5*256*4)   // w2t f32
                      + al((size_t)256*24*128*4)  // wdt f32
                      + 4 * al(2048);             // BN folds
    const size_t need_big = al(x1_big) + al(x2_bytes) + tail;  // 139,091,968

    const bool big = (ws_size >= need_big);
    const int cc = big ? 8 : 4;        // conv chunk (batches per conv launch)
    const size_t shared_bytes = big ? x1_big : sh_small;

    char* ws = (char*)d_ws;
    size_t off = 0;
    auto alloc = [&](size_t bytes) -> char* {
        char* p = ws + off;
        off = (off + bytes + 255) & ~(size_t)255;
        return p;
    };
    char* shared = alloc(shared_bytes);
    double* x1d  = (double*)shared;     // dead when convd runs
    double* parts= (double*)shared;     // aliases x1; parts[0] becomes e (f64)
    double* zd   = (double*)(shared + parts_b);   // per-group z, in parts tail
    double* x2d  = (double*)alloc(x2_bytes);
    float*  w1t  = (float*)alloc((size_t)80*5*256*4);
    float*  w2t  = (float*)alloc((size_t)256*5*256*4);
    float*  wdt  = (float*)alloc((size_t)256*24*128*4);
    double* a1d  = (double*)alloc(2048);
    double* bt1d = (double*)alloc(2048);
    double* a2d  = (double*)alloc(2048);
    double* bt2d = (double*)alloc(2048);

    float* e_out   = (float*)d_out;                          // [16][128][341]
    float* idx_out = (float*)d_out + (size_t)B_ * EMB * TP;  // [8][16][341]

    prep_v11<<<3072, 256, 0, stream>>>(w1, w2, wd, b1, g1, be1, m1, v1,
                                       b2, g2, be2, m2, v2,
                                       w1t, w2t, wdt, a1d, bt1d, a2d, bt2d);

    const int comb_blocks = (nb * EMB * TP + 255) / 256;
    for (int g = 0; g < ngrp; ++g) {
        for (int ch = 0; ch < nb / cc; ++ch) {
            int b_abs = g * nb + ch * cc;
            conv5_v8<CIN1, float>
                <<<dim3(16, 4, cc), 256, 0, stream>>>(
                mel + (size_t)b_abs * CIN1 * T_, w1t, a1d, bt1d,
                x1d + (big ? (size_t)ch * cc * C_ * T_ : 0));
            conv5_v8<C_, double>
                <<<dim3(16, 4, cc), 256, 0, stream>>>(
                x1d + (big ? (size_t)ch * cc * C_ * T_ : 0), w2t, a2d, bt2d,
                x2d + (size_t)ch * cc * C_ * T_);
        }
        // x1 dead from here -> parts may reuse it
        convd_f64_v7<<<dim3(3, 1, nb * nsplit), 256, 0, stream>>>(
            x2d, wdt, parts, nb, nsplit, cis);
        convd_combine<<<comb_blocks, 256, 0, stream>>>(
            parts, bd, e_out, nb, g * nb, nsplit);
        zproj_f64<<<dim3(3, nb), 128, 0, stream>>>(parts, wp, bp, zd);
        rvq_f64_v3<<<nb * TP, 256, 0, stream>>>(zd, cb, idx_out, g * nb * TP);
    }
}

// Round 13
// 1675.270 us; speedup vs baseline: 1.3018x; 1.0686x over previous
//
#include <hip/hip_runtime.h>
#include <math.h>

#define B_    16
#define BCH   4            // batch chunk for conv1/conv2
#define T_    4096
#define C_    256
#define CIN1  80
#define EMB   128
#define STRIDE_ 12
#define TP    341
#define NPOS  (B_*TP)      // 5456
#define NQ_   8
#define KCB   256
#define BN_EPS 1e-5

// ---------------- prep: f64 transposes + BN fold ----------------
__global__ __launch_bounds__(256) void prep_f64(
    const float* __restrict__ w1, const float* __restrict__ w2,
    const float* __restrict__ wd,
    const float* __restrict__ b1, const float* __restrict__ g1,
    const float* __restrict__ be1, const float* __restrict__ m1,
    const float* __restrict__ v1,
    const float* __restrict__ b2, const float* __restrict__ g2,
    const float* __restrict__ be2, const float* __restrict__ m2,
    const float* __restrict__ v2,
    const float* __restrict__ wp, const float* __restrict__ bp,
    double* __restrict__ w1t, double* __restrict__ w2t, double* __restrict__ wdt,
    double* __restrict__ a1, double* __restrict__ bt1,
    double* __restrict__ a2, double* __restrict__ bt2,
    double* __restrict__ wpd, double* __restrict__ bpd)
{
    int j = blockIdx.x * 256 + threadIdx.x;
    if (j < 256*24*128) wdt[j] = (double)wd[(size_t)(j & 127) * 6144 + (j >> 7)];
    if (j < 256*5*256)  w2t[j] = (double)w2[(size_t)(j & 255) * 1280 + (j >> 8)];
    if (j < 80*5*256)   w1t[j] = (double)w1[(size_t)(j & 255) * 400 + (j >> 8)];
    if (j < 16*128)     wpd[j] = (double)wp[j];
    if (j < 16)         bpd[j] = (double)bp[j];
    if (j < 256) {
        double inv1 = 1.0 / sqrt((double)v1[j] + BN_EPS);
        double s1 = (double)g1[j] * inv1;
        a1[j]  = s1;
        bt1[j] = ((double)b1[j] - (double)m1[j]) * s1 + (double)be1[j];
        double inv2 = 1.0 / sqrt((double)v2[j] + BN_EPS);
        double s2 = (double)g2[j] * inv2;
        a2[j]  = s2;
        bt2[j] = ((double)b2[j] - (double)m2[j]) * s2 + (double)be2[j];
    }
}

// bank swizzle on 16B granularity: permutes within aligned 8-block (128B) groups
__device__ __forceinline__ int swz_pair(int col) {        // col even, 16B unit
    int bw = col >> 1;
    return ((bw ^ ((bw >> 3) & 7)) << 1);
}
__device__ __forceinline__ int swz_scalar(int col) {      // any col (8B unit)
    int bw = col >> 1;
    return (((bw ^ ((bw >> 3) & 7)) << 1) | (col & 1));
}

// ---------------- f64 conv(k=5,pad=2) + BN + ReLU ----------------
// block: 64 co x 128 t for one (local) batch. 256 thr: 16 tcol (8 t) x 16 trow (4 co)
// 8-ci chunks -> 29 KB LDS -> 5 blocks/CU. Swizzled x-tile.
template<int CIN, typename Tin>
__global__ __launch_bounds__(256) void conv5_bn_relu_f64(
    const Tin* __restrict__ in,       // [BCH][CIN][T]
    const double* __restrict__ wt,    // [(ci*5+k)][256]
    const double* __restrict__ alpha, const double* __restrict__ beta,
    double* __restrict__ out)         // [BCH][256][T]
{
    const int b   = blockIdx.z;
    const int co0 = blockIdx.y * 64;
    const int t0  = blockIdx.x * 128;
    const int tid = threadIdx.x;
    const int tcol = tid & 15;
    const int trow = tid >> 4;

    __shared__ double xs[8][136];     // 8704 B (132 used, swizzled)
    __shared__ double wsh[40][64];    // 20480 B

    double acc[4][8];
    #pragma unroll
    for (int i = 0; i < 4; ++i)
        #pragma unroll
        for (int j = 0; j < 8; ++j) acc[i][j] = 0.0;

    for (int c0 = 0; c0 < CIN; c0 += 8) {
        for (int i = tid; i < 8 * 132; i += 256) {
            int ci = i / 132, col = i % 132;
            int t = t0 - 2 + col;
            double v = 0.0;
            if (t >= 0 && t < T_) v = (double)in[((size_t)(b * CIN + c0 + ci)) * T_ + t];
            xs[ci][swz_scalar(col)] = v;
        }
        for (int i = tid; i < 40 * 64; i += 256) {
            int r = i >> 6, co = i & 63;
            wsh[r][co] = wt[(size_t)(c0 * 5 + r) * 256 + co0 + co];
        }
        __syncthreads();

        #pragma unroll
        for (int ci = 0; ci < 8; ++ci) {
            double xv[12];
            #pragma unroll
            for (int m = 0; m < 6; ++m) {
                double2 v = *(const double2*)&xs[ci][swz_pair(tcol * 8 + 2 * m)];
                xv[2 * m] = v.x; xv[2 * m + 1] = v.y;
            }
            #pragma unroll
            for (int k = 0; k < 5; ++k) {
                double w0 = wsh[ci * 5 + k][trow * 4 + 0];
                double w1v = wsh[ci * 5 + k][trow * 4 + 1];
                double w2v = wsh[ci * 5 + k][trow * 4 + 2];
                double w3v = wsh[ci * 5 + k][trow * 4 + 3];
                #pragma unroll
                for (int j = 0; j < 8; ++j) {
                    double xq = xv[j + k];
                    acc[0][j] = fma(w0, xq, acc[0][j]);
                    acc[1][j] = fma(w1v, xq, acc[1][j]);
                    acc[2][j] = fma(w2v, xq, acc[2][j]);
                    acc[3][j] = fma(w3v, xq, acc[3][j]);
                }
            }
        }
        __syncthreads();
    }

    const int cobase = co0 + trow * 4;
    const int tg = t0 + tcol * 8;
    #pragma unroll
    for (int i = 0; i < 4; ++i) {
        double a = alpha[cobase + i], bt = beta[cobase + i];
        size_t base = ((size_t)(b * C_ + cobase + i)) * T_ + tg;
        #pragma unroll
        for (int j = 0; j < 8; ++j) {
            double y = fma(acc[i][j], a, bt);
            out[base + j] = y > 0.0 ? y : 0.0;
        }
    }
}

// ---------------- f64 downsample conv v5: k=24, stride=12, pad=6 ----------------
// All nb batches, ci split nsplit ways. block: 64 co x 128 tp; 256 thr:
// crow=tid>>5 (8 co each), tcol=tid&31, tp = tp0 + tcol + 32j (j=0..3).
// Swizzled x-tile; w reads are wave-broadcast. Writes f64 partials.
__global__ __launch_bounds__(256) void convd_f64_v5(
    const double* __restrict__ x2,    // [nb][256][T]
    const double* __restrict__ wdt,   // [(ci*24+k)][128]
    double* __restrict__ parts,       // [nsplit][nb][128][341]
    int nb, int nsplit, int cis)
{
    const int bz  = blockIdx.z;
    const int s   = bz % nsplit;
    const int b   = bz / nsplit;
    const int co0 = blockIdx.y * 64;
    const int tp0 = blockIdx.x * 128;
    const int tid = threadIdx.x;
    const int tcol = tid & 31;
    const int crow = tid >> 5;

    __shared__ double xs[2][1552];    // 24832 B (span 127*12+24=1548, swizzled)
    __shared__ double wsh[48][64];    // 24576 B

    double acc[8][4];
    #pragma unroll
    for (int i = 0; i < 8; ++i)
        #pragma unroll
        for (int j = 0; j < 4; ++j) acc[i][j] = 0.0;

    const int tbase = tp0 * 12 - 6;
    const int ci_begin = s * cis;

    for (int c0 = ci_begin; c0 < ci_begin + cis; c0 += 2) {
        for (int i = tid; i < 2 * 1548; i += 256) {
            int ci = i / 1548, col = i % 1548;
            int t = tbase + col;
            double v = (t >= 0 && t < T_)
                ? x2[((size_t)(b * 256 + c0 + ci)) * T_ + t] : 0.0;
            xs[ci][swz_scalar(col)] = v;
        }
        for (int i = tid; i < 48 * 64; i += 256) {
            int r = i >> 6, c = i & 63;
            wsh[r][c] = wdt[(size_t)(c0 * 24 + r) * 128 + co0 + c];
        }
        __syncthreads();

        #pragma unroll
        for (int ci = 0; ci < 2; ++ci) {
            #pragma unroll
            for (int kk = 0; kk < 12; ++kk) {
                const double* wr0 = &wsh[ci * 24 + 2 * kk][crow * 8];
                const double* wr1 = &wsh[ci * 24 + 2 * kk + 1][crow * 8];
                double2 xp[4];
                #pragma unroll
                for (int j = 0; j < 4; ++j) {
                    // col = (tcol+32j)*12 + 2kk  ->  bw = (tcol+32j)*6 + kk
                    int bw = (tcol + 32 * j) * 6 + kk;
                    int colp = ((bw ^ ((bw >> 3) & 7)) << 1);
                    xp[j] = *(const double2*)&xs[ci][colp];
                }
                #pragma unroll
                for (int i = 0; i < 8; ++i) {
                    double wa = wr0[i], wb = wr1[i];
                    #pragma unroll
                    for (int j = 0; j < 4; ++j) {
                        acc[i][j] = fma(wa, xp[j].x, acc[i][j]);
                        acc[i][j] = fma(wb, xp[j].y, acc[i][j]);
                    }
                }
            }
        }
        __syncthreads();
    }

    #pragma unroll
    for (int i = 0; i < 8; ++i) {
        int co = co0 + crow * 8 + i;
        #pragma unroll
        for (int j = 0; j < 4; ++j) {
            int tp = tp0 + tcol + 32 * j;
            if (tp < TP)
                parts[(((size_t)s * nb + b) * EMB + co) * TP + tp] = acc[i][j];
        }
    }
}

// ---------------- combine partials + bias -> ed (f64) + e_out (f32) ----------------
__global__ __launch_bounds__(256) void convd_combine(
    const double* __restrict__ parts, // [nsplit][nb][128][341]
    const float* __restrict__ bd,
    double* __restrict__ ed,          // [16][128][341] (absolute b)
    float* __restrict__ e_out,        // [16][128][341]
    int nb, int b_off, int nsplit)
{
    int idx = blockIdx.x * 256 + threadIdx.x;
    int total = nb * EMB * TP;
    if (idx >= total) return;
    int b_local = idx / (EMB * TP);
    int rem = idx % (EMB * TP);
    int co = rem / TP;
    size_t stride = (size_t)nb * EMB * TP;
    double y = 0.0;
    for (int s = 0; s < nsplit; ++s)     // ascending s: deterministic
        y += parts[(size_t)s * stride + idx];
    y += (double)bd[co];
    size_t o = (size_t)(b_off + b_local) * EMB * TP + rem;
    ed[o] = y;
    e_out[o] = (float)y;
}

// ---------------- f64 1x1 projection ----------------
__global__ __launch_bounds__(128) void zproj_f64(
    const double* __restrict__ ed,    // [B][128][341]
    const double* __restrict__ wpd,   // [16][128]
    const double* __restrict__ bpd,   // [16]
    double* __restrict__ z)           // [B][341][16]
{
    const int b = blockIdx.y;
    const int t = blockIdx.x * 128 + threadIdx.x;
    __shared__ double wps[16][128];
    for (int i = threadIdx.x; i < 16 * 128; i += 128)
        wps[i >> 7][i & 127] = wpd[i];
    __syncthreads();
    if (t >= TP) return;
    double acc[16];
    #pragma unroll
    for (int v = 0; v < 16; ++v) acc[v] = bpd[v];
    for (int co = 0; co < 128; ++co) {
        double x = ed[((size_t)(b * EMB + co)) * TP + t];
        #pragma unroll
        for (int v = 0; v < 16; ++v) acc[v] = fma(x, wps[v][co], acc[v]);
    }
    #pragma unroll
    for (int v = 0; v < 16; ++v)
        z[((size_t)(b * TP + t)) * 16 + v] = acc[v];
}

// ---------------- RVQ: f64 distances, wave-shuffle argmin ----------------
__global__ __launch_bounds__(256) void rvq_f64_v2(
    const double* __restrict__ z,     // [NPOS][16]
    const float* __restrict__ cb,     // [8][256][16]
    float* __restrict__ out_idx)      // [8][NPOS] as float
{
    const int pos = blockIdx.x;
    const int tid = threadIdx.x;
    const int lane = tid & 63;
    const int wv = tid >> 6;

    __shared__ double r[16];
    __shared__ double wd_s[4];
    __shared__ int wi_s[4];
    __shared__ int best_s;

    if (tid < 16) r[tid] = z[(size_t)pos * 16 + tid];
    __syncthreads();

    for (int q = 0; q < NQ_; ++q) {
        const float* c = cb + ((size_t)(q * KCB) + tid) * 16;
        double d = 0.0;
        #pragma unroll
        for (int i = 0; i < 16; ++i) {
            double diff = r[i] - (double)c[i];
            d = fma(diff, diff, d);
        }
        int idx = tid;
        #pragma unroll
        for (int sft = 32; sft > 0; sft >>= 1) {
            double d2 = __shfl_down(d, sft, 64);
            int i2 = __shfl_down(idx, sft, 64);
            if (d2 < d || (d2 == d && i2 < idx)) { d = d2; idx = i2; }
        }
        if (lane == 0) { wd_s[wv] = d; wi_s[wv] = idx; }
        __syncthreads();
        if (tid == 0) {
            double bd_ = wd_s[0]; int bi = wi_s[0];
            #pragma unroll
            for (int w = 1; w < 4; ++w) {
                if (wd_s[w] < bd_ || (wd_s[w] == bd_ && wi_s[w] < bi)) {
                    bd_ = wd_s[w]; bi = wi_s[w];
                }
            }
            best_s = bi;
            out_idx[(size_t)q * NPOS + pos] = (float)bi;
        }
        __syncthreads();
        int best = best_s;
        if (tid < 16)
            r[tid] = r[tid] - (double)cb[((size_t)(q * KCB) + best) * 16 + tid];
        __syncthreads();
    }
}

// ---------------- host launcher ----------------
extern "C" void kernel_launch(void* const* d_in, const int* in_sizes, int n_in,
                              void* d_out, int out_size, void* d_ws, size_t ws_size,
                              hipStream_t stream) {
    const float* mel = (const float*)d_in[0];
    const float* w1  = (const float*)d_in[1];
    const float* b1  = (const float*)d_in[2];
    const float* g1  = (const float*)d_in[3];
    const float* be1 = (const float*)d_in[4];
    const float* m1  = (const float*)d_in[5];
    const float* v1  = (const float*)d_in[6];
    const float* w2  = (const float*)d_in[7];
    const float* b2  = (const float*)d_in[8];
    const float* g2  = (const float*)d_in[9];
    const float* be2 = (const float*)d_in[10];
    const float* m2  = (const float*)d_in[11];
    const float* v2  = (const float*)d_in[12];
    const float* wd  = (const float*)d_in[13];
    const float* bd  = (const float*)d_in[14];
    const float* wp  = (const float*)d_in[15];
    const float* bp  = (const float*)d_in[16];
    const float* cb  = (const float*)d_in[17];

    auto need = [](int nb, int ns) -> size_t {
        size_t s = 0;
        s += (size_t)BCH * C_ * T_ * 8;                 // x1
        s += (size_t)nb * C_ * T_ * 8;                  // x2
        s += (size_t)80*5*256*8 + (size_t)256*5*256*8 + (size_t)256*24*128*8;
        s += 4 * 2048 + 16384 + 256;                    // BN/proj scalars
        s += (size_t)16 * EMB * TP * 8;                 // ed
        s += (size_t)16 * TP * 16 * 8;                  // zd
        s += (size_t)ns * nb * EMB * TP * 8;            // parts
        s += 16384;                                     // align slack
        return s;
    };
    int nb = 8, nsplit = 8;
    if (ws_size >= need(16, 8))      { nb = 16; nsplit = 8; }
    else if (ws_size >= need(16, 4)) { nb = 16; nsplit = 4; }
    const int ngrp = B_ / nb;
    const int cis  = 256 / nsplit;

    char* ws = (char*)d_ws;
    size_t off = 0;
    auto alloc = [&](size_t bytes) -> char* {
        char* p = ws + off;
        off = (off + bytes + 255) & ~(size_t)255;
        return p;
    };
    double* x1d  = (double*)alloc((size_t)BCH * C_ * T_ * 8);
    double* x2d  = (double*)alloc((size_t)nb * C_ * T_ * 8);
    double* w1td = (double*)alloc((size_t)80*5*256*8);
    double* w2td = (double*)alloc((size_t)256*5*256*8);
    double* wdtd = (double*)alloc((size_t)256*24*128*8);
    double* a1d  = (double*)alloc(2048);
    double* bt1d = (double*)alloc(2048);
    double* a2d  = (double*)alloc(2048);
    double* bt2d = (double*)alloc(2048);
    double* wpd  = (double*)alloc(16*128*8);
    double* bpd  = (double*)alloc(16*8);
    double* ed   = (double*)alloc((size_t)16 * EMB * TP * 8);
    double* zd   = (double*)alloc((size_t)16 * TP * 16 * 8);
    double* parts= (double*)alloc((size_t)nsplit * nb * EMB * TP * 8);

    float* e_out   = (float*)d_out;                          // [16][128][341]
    float* idx_out = (float*)d_out + (size_t)B_ * EMB * TP;  // [8][16][341]

    prep_f64<<<3072, 256, 0, stream>>>(w1, w2, wd, b1, g1, be1, m1, v1,
                                       b2, g2, be2, m2, v2, wp, bp,
                                       w1td, w2td, wdtd, a1d, bt1d, a2d, bt2d,
                                       wpd, bpd);

    const int comb_blocks = (nb * EMB * TP + 255) / 256;
    for (int g = 0; g < ngrp; ++g) {
        for (int ch = 0; ch < nb / BCH; ++ch) {
            int ch_abs = g * (nb / BCH) + ch;
            const float* mel_c = mel + (size_t)ch_abs * BCH * CIN1 * T_;
            conv5_bn_relu_f64<CIN1, float><<<dim3(32, 4, BCH), 256, 0, stream>>>(
                mel_c, w1td, a1d, bt1d, x1d);
            conv5_bn_relu_f64<C_, double><<<dim3(32, 4, BCH), 256, 0, stream>>>(
                x1d, w2td, a2d, bt2d, x2d + (size_t)ch * BCH * C_ * T_);
        }
        convd_f64_v5<<<dim3(3, 2, nb * nsplit), 256, 0, stream>>>(
            x2d, wdtd, parts, nb, nsplit, cis);
        convd_combine<<<comb_blocks, 256, 0, stream>>>(parts, bd, ed, e_out,
                                                       nb, g * nb, nsplit);
    }
    zproj_f64<<<dim3(3, 16), 128, 0, stream>>>(ed, wpd, bpd, zd);
    rvq_f64_v2<<<NPOS, 256, 0, stream>>>(zd, cb, idx_out);
}